// Round 1
// baseline (219.211 us; speedup 1.0000x reference)
//
#include <hip/hip_runtime.h>
#include <stdint.h>

// Problem constants (from reference): B=16, T=2048, C=896, E=4
#define N_TOK 32768
#define C_DIM 896
#define C2    448          // C/2 (float2 elements per token)
#define E_NUM 4
#define CAP   8192         // ceil(N * 1.0 / E)
#define NBINS 16384
#define BASE_BITS 0x3E800000u   // bits of 0.25f (min possible max-softmax prob)

// ws layout (bytes):
//   [0,       262144)  hist       : E * NBINS * u32   (memset 0)
//   [262144,  262160)  candcount  : E * u32           (memset 0)
//   [262160,  344080)  partials   : 2048 * 5 doubles
//   [344080,  475152)  probf      : N floats
//   [475152,  606224)  expert     : N int32
//   [606224,  606288)  params     : E * int4 {mode, bstar, krem, ne}
//   [606288, 1654864)  cand       : E * N * uint2 {pbits, tok}
//   [1654864,1687632)  sel        : N bytes

__device__ __forceinline__ int binOf(uint32_t bits) {
    if (bits <= BASE_BITS) return 0;
    uint32_t d = (bits - BASE_BITS) >> 10;
    return d > 16383u ? 16383 : (int)d;
}

// K1: wave-per-token router. fp64 logits, softmax, argmax; hist + loss partials.
__global__ __launch_bounds__(1024) void k_router(const float2* __restrict__ x2,
                                                 const float* __restrict__ Wg,
                                                 uint32_t* __restrict__ hist,
                                                 double* __restrict__ partials,
                                                 float* __restrict__ probf,
                                                 int* __restrict__ expert)
{
    __shared__ float2 wsh[E_NUM * C2];   // 14336 B
    __shared__ double red[16][5];
    int tid = threadIdx.x;

    float* wf = (float*)wsh;
    for (int i = tid; i < E_NUM * C_DIM; i += 1024) wf[i] = Wg[i];
    __syncthreads();

    int wave = tid >> 6, lane = tid & 63;
    int t = blockIdx.x * 16 + wave;

    double acc0 = 0, acc1 = 0, acc2 = 0, acc3 = 0;
    const float2* xr = x2 + (size_t)t * C2;
#pragma unroll
    for (int k = 0; k < 7; ++k) {
        int c = lane + 64 * k;
        float2 xv = xr[c];
        double dx = (double)xv.x, dy = (double)xv.y;
        float2 w0 = wsh[0 * C2 + c];
        float2 w1 = wsh[1 * C2 + c];
        float2 w2 = wsh[2 * C2 + c];
        float2 w3 = wsh[3 * C2 + c];
        acc0 += dx * (double)w0.x; acc0 += dy * (double)w0.y;
        acc1 += dx * (double)w1.x; acc1 += dy * (double)w1.y;
        acc2 += dx * (double)w2.x; acc2 += dy * (double)w2.y;
        acc3 += dx * (double)w3.x; acc3 += dy * (double)w3.y;
    }
#pragma unroll
    for (int off = 32; off > 0; off >>= 1) {
        acc0 += __shfl_xor(acc0, off);
        acc1 += __shfl_xor(acc1, off);
        acc2 += __shfl_xor(acc2, off);
        acc3 += __shfl_xor(acc3, off);
    }

    if (lane == 0) {
        double m = fmax(fmax(acc0, acc1), fmax(acc2, acc3));
        double e0 = exp(acc0 - m), e1 = exp(acc1 - m), e2 = exp(acc2 - m), e3 = exp(acc3 - m);
        double s = e0 + e1 + e2 + e3;
        double inv = 1.0 / s;
        // first-occurrence argmax (strict >)
        int best = 0; double bl = acc0;
        if (acc1 > bl) { best = 1; bl = acc1; }
        if (acc2 > bl) { best = 2; bl = acc2; }
        if (acc3 > bl) { best = 3; bl = acc3; }
        double pb = (best == 0 ? e0 : best == 1 ? e1 : best == 2 ? e2 : e3) * inv;
        float pf = (float)pb;
        probf[t]  = pf;
        expert[t] = best;
        atomicAdd(&hist[best * NBINS + binOf(__float_as_uint(pf))], 1u);
        double lse = m + log(s);
        red[wave][0] = e0 * inv; red[wave][1] = e1 * inv;
        red[wave][2] = e2 * inv; red[wave][3] = e3 * inv;
        red[wave][4] = lse * lse;
    }
    __syncthreads();
    if (tid < 5) {
        double v = 0.0;
        for (int w = 0; w < 16; ++w) v += red[w][tid];
        partials[(size_t)blockIdx.x * 5 + tid] = v;
    }
}

// K2: reduce loss partials; per-expert cutoff-bin search; write loss scalar.
__global__ __launch_bounds__(1024) void k_reduce(const uint32_t* __restrict__ hist,
                                                 const double* __restrict__ partials,
                                                 int4* __restrict__ params,
                                                 float* __restrict__ out_scalar)
{
    __shared__ double dred[1024];
    __shared__ uint32_t s[1024];
    __shared__ double finals[5];
    __shared__ int ne_sh[E_NUM];
    int tid = threadIdx.x;

    // loss partial reduction: finals[0..3]=P sums, finals[4]=sum lse^2
    for (int c = 0; c < 5; ++c) {
        double v = 0.0;
        for (int r = tid; r < 2048; r += 1024) v += partials[(size_t)r * 5 + c];
        dred[tid] = v; __syncthreads();
        for (int off = 512; off > 0; off >>= 1) {
            if (tid < off) dred[tid] += dred[tid + off];
            __syncthreads();
        }
        if (tid == 0) finals[c] = dred[0];
        __syncthreads();
    }

    // per-expert suffix scan over 16384 bins (1024 chunks x 16 bins)
    for (int e = 0; e < E_NUM; ++e) {
        const uint32_t* h = hist + e * NBINS;
        int lo = tid * 16;
        uint32_t csum = 0;
        for (int b = 0; b < 16; ++b) csum += h[lo + b];
        s[tid] = csum; __syncthreads();
        for (int off = 1; off < 1024; off <<= 1) {
            uint32_t v = (tid + off < 1024) ? s[tid + off] : 0u;
            __syncthreads();
            s[tid] += v;
            __syncthreads();
        }
        uint32_t ne = s[0];
        if (tid == 0) ne_sh[e] = (int)ne;
        if (ne <= (uint32_t)CAP) {
            if (tid == 0) params[e] = make_int4(0, -1, 0, (int)ne);  // ALL selected
        } else {
            uint32_t S_i = s[tid];
            uint32_t S_next = (tid < 1023) ? s[tid + 1] : 0u;
            if (S_i > (uint32_t)CAP && S_next <= (uint32_t)CAP) {
                uint32_t above = S_next;
                for (int b = lo + 15; b >= lo; --b) {
                    uint32_t hb = h[b];
                    if (above + hb > (uint32_t)CAP) {
                        params[e] = make_int4(1, b, (int)((uint32_t)CAP - above), (int)ne);
                        break;
                    }
                    above += hb;
                }
            }
        }
        __syncthreads();
    }

    if (tid == 0) {
        double aux = 0.0;
        for (int e = 0; e < E_NUM; ++e) {
            double f = (double)(ne_sh[e] < CAP ? ne_sh[e] : CAP) / (double)N_TOK;
            double P = finals[e] / (double)N_TOK;
            aux += f * P;
        }
        aux *= 0.01 * (double)E_NUM;
        double z = 0.001 * (finals[4] / (double)N_TOK);
        *out_scalar = (float)(aux + z);
    }
}

// K3a: gather cutoff-bin candidates per expert
__global__ void k_gather(const float* __restrict__ probf, const int* __restrict__ expert,
                         const int4* __restrict__ params, uint32_t* __restrict__ candcount,
                         uint2* __restrict__ cand)
{
    int t = blockIdx.x * blockDim.x + threadIdx.x;
    if (t >= N_TOK) return;
    int e = expert[t];
    int4 pr = params[e];
    if (pr.x != 1) return;
    uint32_t bits = __float_as_uint(probf[t]);
    if (binOf(bits) == pr.y) {
        uint32_t pos = atomicAdd(&candcount[e], 1u);
        cand[(size_t)e * N_TOK + pos] = make_uint2(bits, (uint32_t)t);
    }
}

// K3b: exact rank among candidates (prob desc, index asc), select top krem
__global__ __launch_bounds__(1024) void k_rank(const int4* __restrict__ params,
                                               const uint32_t* __restrict__ candcount,
                                               const uint2* __restrict__ cand,
                                               uint8_t* __restrict__ sel)
{
    int e = blockIdx.x;
    int4 pr = params[e];
    if (pr.x != 1) return;
    int K = (int)candcount[e];
    int krem = pr.z;
    const uint2* ce = cand + (size_t)e * N_TOK;
    for (int i = threadIdx.x; i < K; i += 1024) {
        uint2 ci = ce[i];
        int rank = 0;
        for (int j = 0; j < K; ++j) {
            uint2 cj = ce[j];
            rank += (int)((cj.x > ci.x) || (cj.x == ci.x && cj.y < ci.y));
        }
        sel[ci.y] = (rank < krem) ? (uint8_t)1 : (uint8_t)0;
    }
}

// K4: write gates + dispatch_mask (identical), float4 per token, twice.
__global__ void k_write(const float* __restrict__ probf, const int* __restrict__ expert,
                        const int4* __restrict__ params, const uint8_t* __restrict__ sel,
                        float4* __restrict__ out)
{
    int t = blockIdx.x * blockDim.x + threadIdx.x;
    if (t >= N_TOK) return;
    int e = expert[t];
    int4 pr = params[e];
    float v;
    if (pr.x == 0) {
        v = 1.0f;
    } else {
        int b = binOf(__float_as_uint(probf[t]));
        v = (b > pr.y) ? 1.0f : (b < pr.y ? 0.0f : (sel[t] ? 1.0f : 0.0f));
    }
    float4 o = make_float4(0.f, 0.f, 0.f, 0.f);
    (&o.x)[e] = v;
    out[t] = o;
    out[t + N_TOK] = o;
}

extern "C" void kernel_launch(void* const* d_in, const int* in_sizes, int n_in,
                              void* d_out, int out_size, void* d_ws, size_t ws_size,
                              hipStream_t stream)
{
    const float* x = (const float*)d_in[0];
    const float* W = (const float*)d_in[1];
    float* out = (float*)d_out;
    char* ws = (char*)d_ws;

    uint32_t* hist      = (uint32_t*)(ws);
    uint32_t* candcount = (uint32_t*)(ws + 262144);
    double*   partials  = (double*)  (ws + 262160);
    float*    probf     = (float*)   (ws + 344080);
    int*      expert    = (int*)     (ws + 475152);
    int4*     params    = (int4*)    (ws + 606224);
    uint2*    cand      = (uint2*)   (ws + 606288);
    uint8_t*  sel       = (uint8_t*) (ws + 1654864);

    hipMemsetAsync(ws, 0, 262160, stream);  // hist + candcount

    k_router<<<2048, 1024, 0, stream>>>((const float2*)x, W, hist, partials, probf, expert);
    k_reduce<<<1, 1024, 0, stream>>>(hist, partials, params, out + 262144);
    k_gather<<<N_TOK / 256, 256, 0, stream>>>(probf, expert, params, candcount, cand);
    k_rank<<<E_NUM, 1024, 0, stream>>>(params, candcount, cand, sel);
    k_write<<<N_TOK / 256, 256, 0, stream>>>(probf, expert, params, sel, (float4*)out);
}

// Round 2
// 199.961 us; speedup vs baseline: 1.0963x; 1.0963x over previous
//
#include <hip/hip_runtime.h>
#include <stdint.h>

// Problem constants (from reference): B=16, T=2048, C=896, E=4
#define N_TOK 32768
#define C_DIM 896
#define C2    448          // C/2 (float2 elements per token)
#define E_NUM 4
#define CAP   8192         // ceil(N * 1.0 / E)
#define NBINS 16384
#define BASE_BITS 0x3E800000u   // bits of 0.25f (min possible max-softmax prob)

// ws layout (bytes):
//   [0,       262144)  hist       : E * NBINS * u32   (memset 0)
//   [262144,  262160)  candcount  : E * u32           (memset 0)
//   [262160,  344080)  partials   : 2048 * 5 doubles
//   [344080,  475152)  probf      : N floats
//   [475152,  606224)  expert     : N int32
//   [606224,  606288)  params     : E * int4 {mode, bstar, krem, ne}
//   [606288, 1654864)  cand       : E * N * uint2 {pbits, tok}

__device__ __forceinline__ int binOf(uint32_t bits) {
    if (bits <= BASE_BITS) return 0;
    uint32_t d = (bits - BASE_BITS) >> 10;
    return d > 16383u ? 16383 : (int)d;
}

// K1: wave-per-token router. fp64 logits, softmax, argmax; hist + loss partials.
__global__ __launch_bounds__(1024) void k_router(const float2* __restrict__ x2,
                                                 const float* __restrict__ Wg,
                                                 uint32_t* __restrict__ hist,
                                                 double* __restrict__ partials,
                                                 float* __restrict__ probf,
                                                 int* __restrict__ expert)
{
    __shared__ float2 wsh[E_NUM * C2];   // 14336 B
    __shared__ double red[16][5];
    int tid = threadIdx.x;

    float* wf = (float*)wsh;
    for (int i = tid; i < E_NUM * C_DIM; i += 1024) wf[i] = Wg[i];
    __syncthreads();

    int wave = tid >> 6, lane = tid & 63;
    int t = blockIdx.x * 16 + wave;

    double acc0 = 0, acc1 = 0, acc2 = 0, acc3 = 0;
    const float2* xr = x2 + (size_t)t * C2;
#pragma unroll
    for (int k = 0; k < 7; ++k) {
        int c = lane + 64 * k;
        float2 xv = xr[c];
        double dx = (double)xv.x, dy = (double)xv.y;
        float2 w0 = wsh[0 * C2 + c];
        float2 w1 = wsh[1 * C2 + c];
        float2 w2 = wsh[2 * C2 + c];
        float2 w3 = wsh[3 * C2 + c];
        acc0 += dx * (double)w0.x; acc0 += dy * (double)w0.y;
        acc1 += dx * (double)w1.x; acc1 += dy * (double)w1.y;
        acc2 += dx * (double)w2.x; acc2 += dy * (double)w2.y;
        acc3 += dx * (double)w3.x; acc3 += dy * (double)w3.y;
    }
#pragma unroll
    for (int off = 32; off > 0; off >>= 1) {
        acc0 += __shfl_xor(acc0, off);
        acc1 += __shfl_xor(acc1, off);
        acc2 += __shfl_xor(acc2, off);
        acc3 += __shfl_xor(acc3, off);
    }

    if (lane == 0) {
        double m = fmax(fmax(acc0, acc1), fmax(acc2, acc3));
        double e0 = exp(acc0 - m), e1 = exp(acc1 - m), e2 = exp(acc2 - m), e3 = exp(acc3 - m);
        double s = e0 + e1 + e2 + e3;
        double inv = 1.0 / s;
        int best = 0; double bl = acc0;
        if (acc1 > bl) { best = 1; bl = acc1; }
        if (acc2 > bl) { best = 2; bl = acc2; }
        if (acc3 > bl) { best = 3; bl = acc3; }
        double pb = (best == 0 ? e0 : best == 1 ? e1 : best == 2 ? e2 : e3) * inv;
        float pf = (float)pb;
        probf[t]  = pf;
        expert[t] = best;
        atomicAdd(&hist[best * NBINS + binOf(__float_as_uint(pf))], 1u);
        double lse = m + log(s);
        red[wave][0] = e0 * inv; red[wave][1] = e1 * inv;
        red[wave][2] = e2 * inv; red[wave][3] = e3 * inv;
        red[wave][4] = lse * lse;
    }
    __syncthreads();
    if (tid < 5) {
        double v = 0.0;
        for (int w = 0; w < 16; ++w) v += red[w][tid];
        partials[(size_t)blockIdx.x * 5 + tid] = v;
    }
}

// K2: reduce loss partials; per-expert cutoff-bin search via shfl scans.
__global__ __launch_bounds__(1024) void k_reduce(const uint32_t* __restrict__ hist,
                                                 const double* __restrict__ partials,
                                                 int4* __restrict__ params,
                                                 float* __restrict__ out_scalar)
{
    __shared__ double wred[16][5];
    __shared__ double finals[5];
    __shared__ uint32_t wtot[16], woff[16];
    __shared__ int ne_sh[E_NUM];
    int tid = threadIdx.x, lane = tid & 63, wave = tid >> 6;

    // ---- loss partial reduction (1 sync) ----
    double a0 = 0, a1 = 0, a2 = 0, a3 = 0, a4 = 0;
    for (int r = tid; r < 2048; r += 1024) {
        const double* p = partials + (size_t)r * 5;
        a0 += p[0]; a1 += p[1]; a2 += p[2]; a3 += p[3]; a4 += p[4];
    }
#pragma unroll
    for (int off = 32; off > 0; off >>= 1) {
        a0 += __shfl_xor(a0, off); a1 += __shfl_xor(a1, off);
        a2 += __shfl_xor(a2, off); a3 += __shfl_xor(a3, off);
        a4 += __shfl_xor(a4, off);
    }
    if (lane == 0) {
        wred[wave][0] = a0; wred[wave][1] = a1; wred[wave][2] = a2;
        wred[wave][3] = a3; wred[wave][4] = a4;
    }
    __syncthreads();
    if (tid < 5) {
        double v = 0.0;
        for (int w = 0; w < 16; ++w) v += wred[w][tid];
        finals[tid] = v;
    }

    // ---- per-expert suffix scan over 16384 bins (2 syncs/expert) ----
    for (int e = 0; e < E_NUM; ++e) {
        const uint32_t* h = hist + e * NBINS;
        int lo = tid * 16;
        uint32_t csum = 0;
#pragma unroll
        for (int b = 0; b < 16; ++b) csum += h[lo + b];

        // in-wave inclusive suffix scan (guarded shfl_down)
        uint32_t v = csum;
#pragma unroll
        for (int off = 1; off < 64; off <<= 1) {
            uint32_t u = __shfl_down(v, off);
            if (lane + off < 64) v += u;
        }
        if (lane == 0) wtot[wave] = v;   // wave total
        __syncthreads();
        if (tid < 16) {
            uint32_t tv = wtot[tid];
            uint32_t iv = tv;
#pragma unroll
            for (int off = 1; off < 16; off <<= 1) {
                uint32_t u = __shfl_down(iv, off);
                if (tid + off < 16) iv += u;
            }
            woff[tid] = iv - tv;              // exclusive suffix (higher waves)
            if (tid == 0) ne_sh[e] = (int)iv; // grand total
        }
        __syncthreads();

        uint32_t S = v + woff[wave];          // inclusive suffix at this thread
        uint32_t ne = (uint32_t)ne_sh[e];
        if (ne <= (uint32_t)CAP) {
            if (tid == 0) params[e] = make_int4(0, -1, 0, (int)ne);
        } else if (S > (uint32_t)CAP && S - csum <= (uint32_t)CAP) {
            uint32_t above = S - csum;        // sum of bins above this chunk
            for (int b = lo + 15; b >= lo; --b) {
                uint32_t hb = h[b];
                if (above + hb > (uint32_t)CAP) {
                    params[e] = make_int4(1, b, (int)((uint32_t)CAP - above), (int)ne);
                    break;
                }
                above += hb;
            }
        }
        __syncthreads();   // wtot/woff reused next expert
    }

    if (tid == 0) {
        double aux = 0.0;
        for (int e = 0; e < E_NUM; ++e) {
            double f = (double)(ne_sh[e] < CAP ? ne_sh[e] : CAP) / (double)N_TOK;
            double P = finals[e] / (double)N_TOK;
            aux += f * P;
        }
        aux *= 0.01 * (double)E_NUM;
        double z = 0.001 * (finals[4] / (double)N_TOK);
        *out_scalar = (float)(aux + z);
    }
}

// K3: fused gather + write. Non-cutoff tokens get final value; cutoff-bin
// tokens get provisional 0 and are pushed to cand; k_rank overwrites winners.
__global__ void k_gather_write(const float* __restrict__ probf, const int* __restrict__ expert,
                               const int4* __restrict__ params, uint32_t* __restrict__ candcount,
                               uint2* __restrict__ cand, float4* __restrict__ out)
{
    int t = blockIdx.x * blockDim.x + threadIdx.x;
    if (t >= N_TOK) return;
    int e = expert[t];
    int4 pr = params[e];
    uint32_t bits = __float_as_uint(probf[t]);
    float v;
    if (pr.x == 0) {
        v = 1.0f;
    } else {
        int b = binOf(bits);
        if (b == pr.y) {
            uint32_t pos = atomicAdd(&candcount[e], 1u);
            cand[(size_t)e * N_TOK + pos] = make_uint2(bits, (uint32_t)t);
            v = 0.0f;  // provisional
        } else {
            v = (b > pr.y) ? 1.0f : 0.0f;
        }
    }
    float4 o = make_float4(0.f, 0.f, 0.f, 0.f);
    (&o.x)[e] = v;
    out[t] = o;
    out[t + N_TOK] = o;
}

// K4: exact rank among cutoff-bin candidates (prob desc, index asc);
// winners overwrite their output entries with 1.0 (runs after k_gather_write).
__global__ __launch_bounds__(1024) void k_rank(const int4* __restrict__ params,
                                               const uint32_t* __restrict__ candcount,
                                               const uint2* __restrict__ cand,
                                               float* __restrict__ outf)
{
    int e = blockIdx.x;
    int4 pr = params[e];
    if (pr.x != 1) return;
    int K = (int)candcount[e];
    int krem = pr.z;
    const uint2* ce = cand + (size_t)e * N_TOK;
    for (int i = threadIdx.x; i < K; i += 1024) {
        uint2 ci = ce[i];
        int rank = 0;
        for (int j = 0; j < K; ++j) {
            uint2 cj = ce[j];
            rank += (int)((cj.x > ci.x) || (cj.x == ci.x && cj.y < ci.y));
        }
        if (rank < krem) {
            outf[(size_t)ci.y * 4 + e] = 1.0f;
            outf[((size_t)ci.y + N_TOK) * 4 + e] = 1.0f;
        }
    }
}

extern "C" void kernel_launch(void* const* d_in, const int* in_sizes, int n_in,
                              void* d_out, int out_size, void* d_ws, size_t ws_size,
                              hipStream_t stream)
{
    const float* x = (const float*)d_in[0];
    const float* W = (const float*)d_in[1];
    float* out = (float*)d_out;
    char* ws = (char*)d_ws;

    uint32_t* hist      = (uint32_t*)(ws);
    uint32_t* candcount = (uint32_t*)(ws + 262144);
    double*   partials  = (double*)  (ws + 262160);
    float*    probf     = (float*)   (ws + 344080);
    int*      expert    = (int*)     (ws + 475152);
    int4*     params    = (int4*)    (ws + 606224);
    uint2*    cand      = (uint2*)   (ws + 606288);

    hipMemsetAsync(ws, 0, 262160, stream);  // hist + candcount

    k_router<<<2048, 1024, 0, stream>>>((const float2*)x, W, hist, partials, probf, expert);
    k_reduce<<<1, 1024, 0, stream>>>(hist, partials, params, out + 262144);
    k_gather_write<<<N_TOK / 256, 256, 0, stream>>>(probf, expert, params, candcount, cand, (float4*)out);
    k_rank<<<E_NUM, 1024, 0, stream>>>(params, candcount, cand, out);
}